// Round 9
// baseline (11519.078 us; speedup 1.0000x reference)
//
#include <hip/hip_runtime.h>
#include <hip/hip_cooperative_groups.h>

namespace cg = cooperative_groups;
typedef unsigned int u32;
typedef unsigned long long u64;

#define M_ROWS 2048
#define N_COLS 4096
#define RHO_C 1.0f
#define STEP_C 5e-05f
#define MAX_ITERS_C 100
#define INNER_C 20

// Relaxed agent-scope atomics: IC-coherent, bypass L1/per-XCD L2.
// Correctness of this model validated by R4-R8 (absmax stable 0.0078).
__device__ __forceinline__ u64 ald64(const u64* p) {
    return __hip_atomic_load(p, __ATOMIC_RELAXED, __HIP_MEMORY_SCOPE_AGENT);
}
__device__ __forceinline__ void ast64(u64* p, u64 v) {
    __hip_atomic_store(p, v, __ATOMIC_RELAXED, __HIP_MEMORY_SCOPE_AGENT);
}
__device__ __forceinline__ void push_slot(u64* p, float v, u32 tag) {
    ast64(p, ((u64)tag << 32) | (u64)__float_as_uint(v));
}
// HOT polls: dependent FMA chain between rounds keeps the VALU issuing so
// the CU cannot clock-gate during the sync window (throttle hypothesis).
// junk is threaded through the kernel and "used" by a never-true guard.
__device__ __forceinline__ float4 poll4(const u64* p, u32 tag, float& junk) {
    for (;;) {
        u64 a = ald64(p),     b = ald64(p + 1);
        u64 c = ald64(p + 2), d = ald64(p + 3);
        if (((u32)(a >> 32) == tag) & ((u32)(b >> 32) == tag) &
            ((u32)(c >> 32) == tag) & ((u32)(d >> 32) == tag))
            return make_float4(__uint_as_float((u32)a), __uint_as_float((u32)b),
                               __uint_as_float((u32)c), __uint_as_float((u32)d));
        #pragma unroll
        for (int i = 0; i < 16; ++i) junk = fmaf(junk, 1.0000001f, 1e-7f);
    }
}
__device__ __forceinline__ float2 poll2(const u64* p, u32 tag, float& junk) {
    for (;;) {
        u64 a = ald64(p), b = ald64(p + 1);
        if (((u32)(a >> 32) == tag) & ((u32)(b >> 32) == tag))
            return make_float2(__uint_as_float((u32)a), __uint_as_float((u32)b));
        #pragma unroll
        for (int i = 0; i < 16; ++i) junk = fmaf(junk, 1.0000001f, 1e-7f);
    }
}

// 256 blocks (1/CU) x 1024 threads (16 waves), persistent cooperative kernel.
// Gram form: g = c + rho*(M x - A^T rt), M = A^T A in registers:
// wave w=(cgp=w>>2, rq=w&3); accM[r][4q+e] = M[16b+4rq+r][1024cgp+256q+4l+e].
// Block b owns x entries [16b,16b+16) and rows [8b,8b+8) of A (Ax/s,u,rt).
// Exchange = push-broadcast fused (value,tag) slots into 8 mailbox copies;
// consumer (copy = blk&7) hot-polls its own copy. Exact-tag match => 0xAA
// poison never matches => no init, no grid.sync anywhere.
__global__ __launch_bounds__(1024) void admm_hot(
    const float* __restrict__ A, const float* __restrict__ bvec,
    const float* __restrict__ cvec, float* __restrict__ out,
    u64* __restrict__ xmb, u64* __restrict__ rmb, int fanout)
{
    const int tid  = threadIdx.x;
    const int blk  = blockIdx.x;
    const int lane = tid & 63;
    const int wave = tid >> 6;
    const int cgp  = wave >> 2;
    const int rq   = wave & 3;
    const int cpy  = (fanout == 1) ? 0 : (blk & 7);

    __shared__ float  abuf[4 * N_COLS];  // 64 KB staging (A rows / rt)
    __shared__ float4 xs4[1024];         // 16 KB staged x
    __shared__ float  red[4][16];
    __shared__ float4 gred[64];
    __shared__ float  wl[16], cw[16];
    __shared__ float  sv[8], uv[8], tpart[16], rtnew[8];

    float junk = 0.0f;
    float* xs = reinterpret_cast<float*>(xs4);
    const float4* A4 = reinterpret_cast<const float4*>(A);
    float4* abuf4 = reinterpret_cast<float4*>(abuf);
    const u64* xmyc = xmb + (size_t)cpy * 8192;   // my x mailbox copy
    const u64* rmyc = rmb + (size_t)cpy * 4096;   // my rt mailbox copy

    if (tid < 16) cw[tid] = cvec[blk * 16 + tid];
    if (tid < 8) { sv[tid] = 0.0f; uv[tid] = 0.0f; }

    // ---- precompute register-resident M fragment (block-local) ----
    float accM[4][16];
    #pragma unroll
    for (int r = 0; r < 4; ++r)
        #pragma unroll
        for (int k = 0; k < 16; ++k) accM[r][k] = 0.0f;

    for (int i0 = 0; i0 < M_ROWS; i0 += 4) {
        #pragma unroll
        for (int ii = 0; ii < 4; ++ii)
            abuf4[ii * 1024 + tid] = A4[(size_t)(i0 + ii) * 1024 + tid];
        __syncthreads();
        #pragma unroll
        for (int ii = 0; ii < 4; ++ii) {
            const float*  row  = abuf + ii * N_COLS;
            const float4* row4 = abuf4 + ii * 1024;
            float4 av[4];
            #pragma unroll
            for (int q = 0; q < 4; ++q)
                av[q] = row4[256 * cgp + 64 * q + lane];
            float cb[4];
            #pragma unroll
            for (int r = 0; r < 4; ++r) cb[r] = row[blk * 16 + rq * 4 + r];
            #pragma unroll
            for (int r = 0; r < 4; ++r)
                #pragma unroll
                for (int q = 0; q < 4; ++q) {
                    accM[r][4*q+0] = fmaf(cb[r], av[q].x, accM[r][4*q+0]);
                    accM[r][4*q+1] = fmaf(cb[r], av[q].y, accM[r][4*q+1]);
                    accM[r][4*q+2] = fmaf(cb[r], av[q].z, accM[r][4*q+2]);
                    accM[r][4*q+3] = fmaf(cb[r], av[q].w, accM[r][4*q+3]);
                }
        }
        __syncthreads();
    }

    for (int outer = 0; outer < MAX_ITERS_C; ++outer) {
        // ---- stage rt(state=outer) into abuf[0..2048) ----
        if (outer == 0) {
            abuf[2 * tid]     = bvec[2 * tid];
            abuf[2 * tid + 1] = bvec[2 * tid + 1];
        } else {
            float2 rv = poll2(rmyc + (outer & 1) * 2048 + 2 * tid,
                              (u32)outer, junk);
            abuf[2 * tid]     = rv.x;
            abuf[2 * tid + 1] = rv.y;
        }
        __syncthreads();

        // ---- w-phase: wl = (A^T rt)[16b..16b+16) ----
        {
            const int p = tid >> 2, gq = tid & 3;
            float4 acc = {0.f, 0.f, 0.f, 0.f};
            #pragma unroll
            for (int k2 = 0; k2 < 8; ++k2) {
                const int i = p + 256 * k2;
                const float tv = abuf[i];
                float4 a = A4[(size_t)i * 1024 + blk * 4 + gq];
                acc.x = fmaf(a.x, tv, acc.x); acc.y = fmaf(a.y, tv, acc.y);
                acc.z = fmaf(a.z, tv, acc.z); acc.w = fmaf(a.w, tv, acc.w);
            }
            #pragma unroll
            for (int off = 4; off < 64; off <<= 1) {
                acc.x += __shfl_xor(acc.x, off);
                acc.y += __shfl_xor(acc.y, off);
                acc.z += __shfl_xor(acc.z, off);
                acc.w += __shfl_xor(acc.w, off);
            }
            if ((lane >> 2) == 0) gred[wave * 4 + gq] = acc;
        }
        __syncthreads();
        if (tid < 4) {
            float4 tot = {0.f, 0.f, 0.f, 0.f};
            #pragma unroll
            for (int w = 0; w < 16; ++w) {
                float4 v = gred[w * 4 + tid];
                tot.x += v.x; tot.y += v.y; tot.z += v.z; tot.w += v.w;
            }
            wl[tid * 4 + 0] = tot.x; wl[tid * 4 + 1] = tot.y;
            wl[tid * 4 + 2] = tot.z; wl[tid * 4 + 3] = tot.w;
        }
        __syncthreads();

        // ---- inner PGD: x <- relu(x - step*(c + rho*(Mx - wl))) ----
        for (int inner = 0; inner < INNER_C; ++inner) {
            const u32 gs = (u32)(outer * INNER_C + inner);  // state consumed

            if (gs == 0) {
                xs4[tid] = make_float4(0.f, 0.f, 0.f, 0.f);
                __syncthreads();
            } else if (inner > 0) {
                float4 xv = poll4(xmyc + (gs & 1) * 4096 + 4 * tid, gs, junk);
                // prev-iter xs4 reads all precede prev S1 -> write is safe now
                xs4[tid] = xv;
                __syncthreads();   // staged
            }
            // inner==0 && outer>0: xs4 already holds state gs (Ax staging)

            float4 xq[4];
            #pragma unroll
            for (int q = 0; q < 4; ++q)
                xq[q] = xs4[256 * cgp + 64 * q + lane];

            float4 pd = {0.f, 0.f, 0.f, 0.f};
            #pragma unroll
            for (int q = 0; q < 4; ++q) {
                pd.x = fmaf(accM[0][4*q+0], xq[q].x, pd.x);
                pd.x = fmaf(accM[0][4*q+1], xq[q].y, pd.x);
                pd.x = fmaf(accM[0][4*q+2], xq[q].z, pd.x);
                pd.x = fmaf(accM[0][4*q+3], xq[q].w, pd.x);
                pd.y = fmaf(accM[1][4*q+0], xq[q].x, pd.y);
                pd.y = fmaf(accM[1][4*q+1], xq[q].y, pd.y);
                pd.y = fmaf(accM[1][4*q+2], xq[q].z, pd.y);
                pd.y = fmaf(accM[1][4*q+3], xq[q].w, pd.y);
                pd.z = fmaf(accM[2][4*q+0], xq[q].x, pd.z);
                pd.z = fmaf(accM[2][4*q+1], xq[q].y, pd.z);
                pd.z = fmaf(accM[2][4*q+2], xq[q].z, pd.z);
                pd.z = fmaf(accM[2][4*q+3], xq[q].w, pd.z);
                pd.w = fmaf(accM[3][4*q+0], xq[q].x, pd.w);
                pd.w = fmaf(accM[3][4*q+1], xq[q].y, pd.w);
                pd.w = fmaf(accM[3][4*q+2], xq[q].z, pd.w);
                pd.w = fmaf(accM[3][4*q+3], xq[q].w, pd.w);
            }
            #pragma unroll
            for (int off = 32; off; off >>= 1) {
                pd.x += __shfl_xor(pd.x, off);
                pd.y += __shfl_xor(pd.y, off);
                pd.z += __shfl_xor(pd.z, off);
                pd.w += __shfl_xor(pd.w, off);
            }
            if (lane == 0) {
                red[cgp][rq * 4 + 0] = pd.x;
                red[cgp][rq * 4 + 1] = pd.y;
                red[cgp][rq * 4 + 2] = pd.z;
                red[cgp][rq * 4 + 3] = pd.w;
            }
            __syncthreads();     // S1: red ready (also orders xs4 reads)

            if (tid < fanout * 16) {
                const int dst = tid >> 4, jj = tid & 15;
                const float y = red[0][jj] + red[1][jj]
                              + red[2][jj] + red[3][jj];
                const float g = cw[jj] + RHO_C * (y - wl[jj]);
                float xn = xs[blk * 16 + jj] - STEP_C * g;
                xn = xn > 0.f ? xn : 0.f;
                push_slot(xmb + (size_t)dst * 8192 + ((gs + 1) & 1) * 4096
                              + blk * 16 + jj, xn, gs + 1);
            }
            // no drain, no tag store: next poll IS the sync
        }

        // ---- Ax phase: needs x state gsf = (outer+1)*INNER_C ----
        {
            const u32 gsf = (u32)((outer + 1) * INNER_C);
            float4 xv = poll4(xmyc + (gsf & 1) * 4096 + 4 * tid, gsf, junk);
            xs4[tid] = xv;       // prior xs4 reads precede inner-19's S1
            __syncthreads();
        }
        {
            const int r = blk * 8 + (wave >> 1), h = wave & 1;
            const float4* Ar = A4 + (size_t)r * 1024 + h * 512;
            const float4* xh = xs4 + h * 512;
            float4 acc = {0.f, 0.f, 0.f, 0.f};
            #pragma unroll
            for (int it = 0; it < 8; ++it) {
                float4 a = Ar[it * 64 + lane], xv = xh[it * 64 + lane];
                acc.x = fmaf(a.x, xv.x, acc.x); acc.y = fmaf(a.y, xv.y, acc.y);
                acc.z = fmaf(a.z, xv.z, acc.z); acc.w = fmaf(a.w, xv.w, acc.w);
            }
            float d = acc.x + acc.y + acc.z + acc.w;
            #pragma unroll
            for (int off = 32; off; off >>= 1) d += __shfl_xor(d, off);
            if (lane == 0) tpart[wave] = d;
        }
        __syncthreads();
        if (tid < 8) {
            const int i = blk * 8 + tid;
            const float a  = tpart[2 * tid] + tpart[2 * tid + 1];
            const float bb = bvec[i];
            const float uu = uv[tid];
            float sn = a - bb + uu; sn = sn > 0.f ? sn : 0.f;
            const float un = uu + a - sn - bb;
            sv[tid] = sn; uv[tid] = un;
            rtnew[tid] = sn + bb - un;
        }
        __syncthreads();
        if (tid < fanout * 8) {
            const int dst = tid >> 3, jj = tid & 7;
            push_slot(rmb + (size_t)dst * 4096 + ((outer + 1) & 1) * 2048
                          + blk * 8 + jj, rtnew[jj], (u32)(outer + 1));
        }
    }

    // ---- outputs: [x(4096), s(2048), u(2048), -u(2048)] ----
    // xs4 holds final x (state 2000, staged in the last Ax phase).
    if (tid < 16) out[blk * 16 + tid] = xs[blk * 16 + tid];
    if (tid < 8) {
        const int i = blk * 8 + tid;
        out[4096 + i] = sv[tid];
        out[6144 + i] = uv[tid];
        out[8192 + i] = -uv[tid];
    }
    // never-true guard: keeps the anti-clock-gate FMA chain alive
    if (__float_as_uint(junk) == 0x7f800001u) out[0] = junk;
}

extern "C" void kernel_launch(void* const* d_in, const int* in_sizes, int n_in,
                              void* d_out, int out_size, void* d_ws, size_t ws_size,
                              hipStream_t stream) {
    const float* A    = (const float*)d_in[0];   // 2048*4096
    const float* bvec = (const float*)d_in[1];   // 2048
    const float* cvec = (const float*)d_in[2];   // 4096
    float* out = (float*)d_out;

    // fanout=8: xmb 8*8192*8B = 512 KiB, rmb 8*4096*8B = 256 KiB.
    int fanout = (ws_size >= (size_t)(1 << 20)) ? 8 : 1;
    u64* xmb = (u64*)d_ws;
    u64* rmb = xmb + (size_t)fanout * 8192;

    void* args[] = { (void*)&A, (void*)&bvec, (void*)&cvec, (void*)&out,
                     (void*)&xmb, (void*)&rmb, (void*)&fanout };
    hipError_t err = hipLaunchCooperativeKernel((const void*)admm_hot,
                               dim3(256), dim3(1024), args, 0, stream);
    (void)err;
}